// Round 2
// baseline (111.538 us; speedup 1.0000x reference)
//
#include <hip/hip_runtime.h>

// DropDim: out[b,t,d] = h[b,t,d] * (mask[b,d] != 0)
// B=16, T=4096, D=1024. h: f32, mask: int32 keep-mask.
// Memory-bound: 256 MiB read + 256 MiB write; mask 64 KiB (cache-resident).
// Roofline: 536.9 MB / 6.3 TB/s ~ 85 us (harness fillBuffer shows ~7 TB/s).
//
// R2 structure: block -> (b, t-chunk). Each 256-thread block covers the full
// D=1024 row (thread = one float4 chunk of d, fixed for its lifetime), so the
// mask is loaded ONCE per thread into a register multiplier; the inner t-loop
// is a pure float4 copy-with-scale at constant 4 KiB stride, unrolled x8 for
// memory-level parallelism. No per-iteration index math, no per-iter mask load.

#define TT 4096
#define DD 1024
#define BLOCKS_PER_B 128          // T chunking: 4096/128 = 32 t-rows per block
#define T_PER_BLOCK (TT / BLOCKS_PER_B)
#define D4 (DD / 4)               // 256 float4 chunks per row == blockDim

__global__ void __launch_bounds__(256)
DropDim_kernel(const float4* __restrict__ h,
               const int4* __restrict__ mask,
               float4* __restrict__ out) {
    const int b   = blockIdx.x >> 7;          // /BLOCKS_PER_B
    const int tc  = blockIdx.x & (BLOCKS_PER_B - 1);
    const int tid = threadIdx.x;              // == d4 chunk index

    // One mask load per thread, ever. 64 KiB total -> L2 hit.
    int4 m = mask[(b << 8) + tid];
    float4 f;
    f.x = m.x ? 1.0f : 0.0f;
    f.y = m.y ? 1.0f : 0.0f;
    f.z = m.z ? 1.0f : 0.0f;
    f.w = m.w ? 1.0f : 0.0f;

    // Base offset: b*T*D/4 + tc*T_PER_BLOCK*D/4 + tid
    const long base = ((long)b << 20) + ((long)(tc * T_PER_BLOCK) << 8) + tid;
    const float4* __restrict__ src = h + base;
    float4* __restrict__ dst = out + base;

    #pragma unroll 8
    for (int t = 0; t < T_PER_BLOCK; ++t) {
        float4 v = src[t << 8];   // stride D/4 = 256 float4 = 4 KiB, coalesced
        v.x *= f.x;
        v.y *= f.y;
        v.z *= f.z;
        v.w *= f.w;
        dst[t << 8] = v;
    }
}

extern "C" void kernel_launch(void* const* d_in, const int* in_sizes, int n_in,
                              void* d_out, int out_size, void* d_ws, size_t ws_size,
                              hipStream_t stream) {
    const float4* h    = (const float4*)d_in[0];
    const int4*   mask = (const int4*)d_in[1];
    float4*       out  = (float4*)d_out;

    const int block = 256;
    const int grid  = 16 * BLOCKS_PER_B;   // 2048 blocks: 8/CU, full occupancy

    DropDim_kernel<<<grid, block, 0, stream>>>(h, mask, out);
}

// Round 4
// 84.014 us; speedup vs baseline: 1.3276x; 1.3276x over previous
//
#include <hip/hip_runtime.h>

// DropDim: out[b,t,d] = h[b,t,d] * (mask[b,d] != 0)
// B=16, T=4096, D=1024. h: f32, mask: int32 keep-mask.
// Memory-bound: 256 MiB read + 256 MiB write; mask 64 KiB (cache-resident).
//
// R4 = R3 with the compile fix: __builtin_nontemporal_store requires a clang
// native vector type (ext_vector_type), not HIP_vector_type<float,4>.
// Rationale unchanged: out is written once and never re-read -> NT stores
// avoid allocating the 256 MiB write stream in L2/LLC, so h (exactly
// L3-sized, 256 MiB) stays Infinity-Cache-resident across timed replays.

typedef float f32x4 __attribute__((ext_vector_type(4)));
typedef int   i32x4 __attribute__((ext_vector_type(4)));

#define TT 4096
#define DD 1024
#define BLOCKS_PER_B 128          // 4096/128 = 32 t-rows per block
#define T_PER_BLOCK (TT / BLOCKS_PER_B)

__global__ void __launch_bounds__(256)
DropDim_kernel(const f32x4* __restrict__ h,
               const i32x4* __restrict__ mask,
               f32x4* __restrict__ out) {
    const int b   = blockIdx.x >> 7;          // /BLOCKS_PER_B
    const int tc  = blockIdx.x & (BLOCKS_PER_B - 1);
    const int tid = threadIdx.x;              // d4 chunk index, fixed per thread

    // One mask load per thread, ever. 64 KiB total -> cache hit.
    i32x4 m = mask[(b << 8) + tid];
    f32x4 f;
    f.x = m.x ? 1.0f : 0.0f;
    f.y = m.y ? 1.0f : 0.0f;
    f.z = m.z ? 1.0f : 0.0f;
    f.w = m.w ? 1.0f : 0.0f;

    // base = b*T*D/4 + tc*T_PER_BLOCK*D/4 + tid
    const long base = ((long)b << 20) + ((long)(tc * T_PER_BLOCK) << 8) + tid;
    const f32x4* __restrict__ src = h + base;
    f32x4* __restrict__ dst = out + base;

    #pragma unroll 8
    for (int t = 0; t < T_PER_BLOCK; ++t) {
        f32x4 v = src[t << 8];    // regular load: let h stay LLC-resident
        v *= f;
        // NT store: out has zero reuse; don't allocate in L2/LLC.
        __builtin_nontemporal_store(v, &dst[t << 8]);
    }
}

extern "C" void kernel_launch(void* const* d_in, const int* in_sizes, int n_in,
                              void* d_out, int out_size, void* d_ws, size_t ws_size,
                              hipStream_t stream) {
    const f32x4* h    = (const f32x4*)d_in[0];
    const i32x4* mask = (const i32x4*)d_in[1];
    f32x4*       out  = (f32x4*)d_out;

    const int block = 256;
    const int grid  = 16 * BLOCKS_PER_B;   // 2048 blocks: 8/CU

    DropDim_kernel<<<grid, block, 0, stream>>>(h, mask, out);
}

// Round 5
// 82.151 us; speedup vs baseline: 1.3577x; 1.0227x over previous
//
#include <hip/hip_runtime.h>

// DropDim: out[b,t,d] = h[b,t,d] * (mask[b,d] != 0)
// B=16, T=4096, D=1024. h: f32, mask: int32 keep-mask.
// Memory-bound: 256 MiB read + 256 MiB write; mask 64 KiB (cache-resident).
//
// R5 = R4 (NT stores, register-resident mask) + finer block granularity:
// 4096 blocks x 16 t-rows (was 2048 x 32) so the device is 2x oversubscribed
// in blocks -> scheduler can overlap block drain tails; full unroll.
//
// Steady-state model (R4 counters): out's NT write stream still transits the
// memory-side Infinity Cache, so h gets ~50% L3 retention (FETCH=128 MiB);
// logical BW 6.4 TB/s already exceeds the 6.3 TB/s copy ceiling. This round
// chases the last few % from occupancy/tail overlap.

typedef float f32x4 __attribute__((ext_vector_type(4)));
typedef int   i32x4 __attribute__((ext_vector_type(4)));

#define TT 4096
#define DD 1024
#define BLOCKS_PER_B 256          // 4096/256 = 16 t-rows per block
#define T_PER_BLOCK (TT / BLOCKS_PER_B)

__global__ void __launch_bounds__(256)
DropDim_kernel(const f32x4* __restrict__ h,
               const i32x4* __restrict__ mask,
               f32x4* __restrict__ out) {
    const int b   = blockIdx.x >> 8;             // /BLOCKS_PER_B
    const int tc  = blockIdx.x & (BLOCKS_PER_B - 1);
    const int tid = threadIdx.x;                 // d4 chunk index, fixed per thread

    // One mask load per thread, ever. 64 KiB total -> cache hit.
    i32x4 m = mask[(b << 8) + tid];
    f32x4 f;
    f.x = m.x ? 1.0f : 0.0f;
    f.y = m.y ? 1.0f : 0.0f;
    f.z = m.z ? 1.0f : 0.0f;
    f.w = m.w ? 1.0f : 0.0f;

    // base = b*T*D/4 + tc*T_PER_BLOCK*D/4 + tid
    const long base = ((long)b << 20) + ((long)(tc * T_PER_BLOCK) << 8) + tid;
    const f32x4* __restrict__ src = h + base;
    f32x4* __restrict__ dst = out + base;

    #pragma unroll
    for (int t = 0; t < T_PER_BLOCK; ++t) {
        f32x4 v = src[t << 8];    // regular load: partial LLC residency for h
        v *= f;
        // NT store: out has zero reuse; minimize its cache footprint.
        __builtin_nontemporal_store(v, &dst[t << 8]);
    }
}

extern "C" void kernel_launch(void* const* d_in, const int* in_sizes, int n_in,
                              void* d_out, int out_size, void* d_ws, size_t ws_size,
                              hipStream_t stream) {
    const f32x4* h    = (const f32x4*)d_in[0];
    const i32x4* mask = (const i32x4*)d_in[1];
    f32x4*       out  = (f32x4*)d_out;

    const int block = 256;
    const int grid  = 16 * BLOCKS_PER_B;   // 4096 blocks: 2x wave-capacity oversubscription

    DropDim_kernel<<<grid, block, 0, stream>>>(h, mask, out);
}